// Round 3
// 407.636 us; speedup vs baseline: 1.0028x; 1.0028x over previous
//
#include <hip/hip_runtime.h>

#define B_TOT 8192
#define NN 64
#define FF 32
#define ITERS 48
#define THRESH 0.35f

// ws layout: [0..3] int Tmax (atomicMax target, memset to 0 each launch),
//            [16 .. 16 + B*48) unsigned char selection indices per batch.

// This is the proven 409us kernel (exact arithmetic, loop structure, and LDS
// access pattern) plus ONE numerics-invariant change: srow is pinned into
// VGPRs after the exp pass (empty asm). VGPR=68 in the proven build showed
// the compiler was rematerializing the gain loop's own-row reads from the
// sims LDS array (16 extra ds_read_b128 per greedy iteration). Pinning makes
// the gain loop read registers instead, halving greedy-loop LDS traffic
// (the measured bottleneck: ~245us of LDS-pipe time out of 345us).
__global__ __launch_bounds__(64) void gat_greedy_kernel(
    const float* __restrict__ mail,
    const float* __restrict__ attn_w,
    const float* __restrict__ src_norm,
    int* __restrict__ tmax_ws,
    unsigned char* __restrict__ sels_ws)
{
    const int b = blockIdx.x;
    const int lane = threadIdx.x;

    // sims row stride 65: lane-varying reads sims[sel*65+lane] hit banks
    // (sel+lane)%32 -> 2-way aliasing only (free on CDNA4).
    __shared__ __align__(16) float sims[NN * 65];
    __shared__ __align__(16) float c_lds[NN];
    __shared__ float qarr[NN];
    __shared__ float sarr[NN];

    // ---- load own raw mail row into registers ----
    const float* __restrict__ myrow = mail + ((size_t)b * NN + lane) * FF;
    float a[FF];
#pragma unroll
    for (int k = 0; k < 8; ++k) {
        const float4 v = reinterpret_cast<const float4*>(myrow)[k];
        a[4*k+0] = v.x; a[4*k+1] = v.y; a[4*k+2] = v.z; a[4*k+3] = v.w;
    }
    const float sn = src_norm[b * NN + lane];

    // |a|^2 with the SAME 4-accumulator tree as the dot below (diag consistency)
    float q0 = 0.f, q1 = 0.f, q2 = 0.f, q3 = 0.f;
#pragma unroll
    for (int k = 0; k < 8; ++k) {
        q0 = fmaf(a[4*k+0], a[4*k+0], q0);
        q1 = fmaf(a[4*k+1], a[4*k+1], q1);
        q2 = fmaf(a[4*k+2], a[4*k+2], q2);
        q3 = fmaf(a[4*k+3], a[4*k+3], q3);
    }
    const float q = (q0 + q1) + (q2 + q3);

    // logits: (sigma_n * a_n) . w  computed as sigma_n * (a_n . w)
    float lg = 0.f;
#pragma unroll
    for (int f = 0; f < FF; ++f) lg = fmaf(a[f], attn_w[f], lg);
    lg *= sn;

    qarr[lane] = q;
    sarr[lane] = sn;
    __syncthreads();

    // ---- softmax over the 64 neighbors (wave butterfly) ----
    float mx = lg;
#pragma unroll
    for (int off = 32; off > 0; off >>= 1)
        mx = fmaxf(mx, __shfl_xor(mx, off, 64));
    const float ex = __expf(lg - mx);
    float se = ex;
#pragma unroll
    for (int off = 32; off > 0; off >>= 1)
        se += __shfl_xor(se, off, 64);
    const float attn = ex / se;

    // ---- pairwise distances: lane n computes row n via Gram trick.
    // Row m operand address is wave-uniform -> scalar (s_load) path.
    const float sqn = sn * sn * q;
    float dsum = 0.f;
    for (int m = 0; m < NN; ++m) {
        const float4* __restrict__ Am =
            reinterpret_cast<const float4*>(mail + ((size_t)b * NN + m) * FF);
        float g0 = 0.f, g1 = 0.f, g2 = 0.f, g3 = 0.f;
#pragma unroll
        for (int k = 0; k < 8; ++k) {
            const float4 v = Am[k];
            g0 = fmaf(a[4*k+0], v.x, g0);
            g1 = fmaf(a[4*k+1], v.y, g1);
            g2 = fmaf(a[4*k+2], v.z, g2);
            g3 = fmaf(a[4*k+3], v.w, g3);
        }
        const float g  = (g0 + g1) + (g2 + g3);
        const float sm = sarr[m];
        const float qm = qarr[m];
        const float sqm = sm * sm * qm;
        const float d2  = (sqn - 2.f * (sn * sm) * g) + sqm;
        const float d   = sqrtf(fmaxf(d2, 0.f));
        dsum += d;
        sims[lane * 65 + m] = d;   // stash distance; exp applied after mean known
    }

    // per-batch mean distance
    float tot = dsum;
#pragma unroll
    for (int off = 32; off > 0; off >>= 1)
        tot += __shfl_xor(tot, off, 64);
    const float meand = tot * (1.f / (float)(NN * NN));
    const float inv   = -1.f / meand;   // SIGMA = 1

    // sims = exp(-d/mean); keep a register copy of own row for the greedy loop
    float srow[NN];
#pragma unroll
    for (int m = 0; m < NN; ++m) {
        const float d = sims[lane * 65 + m];
        const float s = __expf(d * inv);
        srow[m] = s;
        sims[lane * 65 + m] = s;
    }
    // Pin srow into VGPRs: without this the compiler rematerializes srow
    // from the sims LDS row inside the greedy loop (16 ds_read_b128/iter).
    // Empty asm copies the SAME bits -> numerics provably unchanged.
#pragma unroll
    for (int m = 0; m < NN; ++m)
        asm volatile("" : "+v"(srow[m]));

    c_lds[lane] = 0.f;
    float c_reg = 0.f;
    __syncthreads();

    // ---- greedy loop: all 48 iterations (global stop resolved later via Tmax) ----
    int firstBelow = ITERS;      // == T_b (prefix length with maxgain >= THRESH)
    bool seenBelow = false;

    for (int t = 0; t < ITERS; ++t) {
        // gain_n = attn_n * sum_m relu(s_nm - c_m)   (reference-accurate form)
        float gain = 0.f;
#pragma unroll
        for (int k = 0; k < 16; ++k) {
            const float4 cv = reinterpret_cast<const float4*>(c_lds)[k];  // uniform b128 broadcast
            gain += fmaxf(srow[4*k+0] - cv.x, 0.f);
            gain += fmaxf(srow[4*k+1] - cv.y, 0.f);
            gain += fmaxf(srow[4*k+2] - cv.z, 0.f);
            gain += fmaxf(srow[4*k+3] - cv.w, 0.f);
        }
        gain *= attn;

        // argmax with FIRST-index tie-break (matches jnp.argmax, incl. all-zero tail)
        float gv = gain; int gi = lane;
#pragma unroll
        for (int off = 32; off > 0; off >>= 1) {
            const float ov = __shfl_xor(gv, off, 64);
            const int   oi = __shfl_xor(gi, off, 64);
            if (ov > gv || (ov == gv && oi < gi)) { gv = ov; gi = oi; }
        }

        if (!seenBelow && gv < THRESH) { firstBelow = t; seenBelow = true; }
        if (lane == 0) sels_ws[(size_t)b * ITERS + t] = (unsigned char)gi;

        // cache update: lane m handles column m (conflict-free stride-65 read)
        const float srl = sims[gi * 65 + lane];
        c_reg = fmaxf(c_reg, srl);
        c_lds[lane] = c_reg;
        __syncthreads();   // single-wave block: cheap; guards LDS RAW ordering
    }

    if (lane == 0) atomicMax(tmax_ws, firstBelow);
}

__global__ __launch_bounds__(64) void gat_accum_kernel(
    const float* __restrict__ mail,
    const float* __restrict__ src_norm,
    const float* __restrict__ dst_norm,
    const int* __restrict__ tmax_ws,
    const unsigned char* __restrict__ sels_ws,
    float* __restrict__ out)
{
    const int lane = threadIdx.x & 31;
    const int b = blockIdx.x * 2 + (threadIdx.x >> 5);
    // contributions happen for t = 0 .. min(47, Tmax)  (append-then-check)
    const int C = min(ITERS, *tmax_ws + 1);
    const unsigned char* __restrict__ sb = sels_ws + (size_t)b * ITERS;
    float acc = 0.f;
    for (int t = 0; t < C; ++t) {
        const int sel = sb[t];
        acc = fmaf(mail[((size_t)b * NN + sel) * FF + lane],
                   src_norm[b * NN + sel], acc);
    }
    out[b * FF + lane] = acc * dst_norm[b];
}

extern "C" void kernel_launch(void* const* d_in, const int* in_sizes, int n_in,
                              void* d_out, int out_size, void* d_ws, size_t ws_size,
                              hipStream_t stream)
{
    const float* mail     = (const float*)d_in[0];
    const float* attn_w   = (const float*)d_in[1];
    const float* src_norm = (const float*)d_in[2];
    const float* dst_norm = (const float*)d_in[3];
    float* out = (float*)d_out;

    int* tmax_ws = (int*)d_ws;
    unsigned char* sels_ws = (unsigned char*)d_ws + 16;

    hipMemsetAsync(d_ws, 0, 4, stream);   // zero the Tmax word (ws is re-poisoned 0xAA)
    gat_greedy_kernel<<<dim3(B_TOT), dim3(64), 0, stream>>>(
        mail, attn_w, src_norm, tmax_ws, sels_ws);
    gat_accum_kernel<<<dim3(B_TOT / 2), dim3(64), 0, stream>>>(
        mail, src_norm, dst_norm, tmax_ws, sels_ws, out);
}